// Round 1
// baseline (156.783 us; speedup 1.0000x reference)
//
#include <hip/hip_runtime.h>

// Problem geometry (from reference setup_inputs): B=8, H=512, W=512, HID=64, T=16.
#define BB 8
#define HH 512
#define WW 512
#define WORDS_PER_ROW (WW / 32)   // 16

// ---------------------------------------------------------------------------
// Kernel 1: build the 512-entry rule LUT.
// Pattern p (9 bits, bit n = neighbor n in row-major 3x3 order):
//   h_k = relu( b1[k] + sum_{n: bit n set} W1[n,k] ),  logit = b2 + sum_k h_k*W2[k]
//   rule bit = (sigmoid(logit) > 0.5) == (logit > 0)
// One block of 512 threads; ballot packs 512 bits into 8 u64 words.
// ---------------------------------------------------------------------------
__global__ void build_lut(const float* __restrict__ W1, const float* __restrict__ b1,
                          const float* __restrict__ W2, const float* __restrict__ b2,
                          int hid, unsigned long long* __restrict__ lut64) {
    int p = threadIdx.x;  // 0..511
    float logit = b2[0];
    for (int k = 0; k < hid; ++k) {
        float a = b1[k];
#pragma unroll
        for (int n = 0; n < 9; ++n)
            if (p & (1 << n)) a += W1[n * hid + k];
        logit += fmaxf(a, 0.0f) * W2[k];
    }
    unsigned long long m = __ballot(logit > 0.0f);
    if ((p & 63) == 0) lut64[p >> 6] = m;
}

// ---------------------------------------------------------------------------
// Kernel 2: out[0] = f0 (verbatim floats); bit-pack (f0 > 0.5) into field.
// Grid covers exactly N cells (N % 256 == 0). One u64 store per wave via ballot.
// ---------------------------------------------------------------------------
__global__ __launch_bounds__(256) void init_field(const float* __restrict__ f0,
                                                  float* __restrict__ out,
                                                  unsigned long long* __restrict__ field) {
    int c = blockIdx.x * 256 + threadIdx.x;
    float v = f0[c];
    out[c] = v;
    unsigned long long m = __ballot(v > 0.5f);
    if ((threadIdx.x & 63) == 0) field[c >> 6] = m;
}

// ---------------------------------------------------------------------------
// Kernel 3: one CA step. Each thread = one cell.
//   window bits (columns w-1..w+1) per row r:  ext = ((next<<32|cur)<<1)|(prev>>31)
//   idx = up3 | mid3<<3 | dn3<<6 ; bit = LUT[idx] ; out = (float)bit
// Fields are bit-packed u32 words, 16 words/row, per image 512*16 words.
// ---------------------------------------------------------------------------
__global__ __launch_bounds__(256) void step_kernel(const unsigned int* __restrict__ Fcur,
                                                   unsigned long long* __restrict__ Fnext,
                                                   const unsigned int* __restrict__ lut32,
                                                   float* __restrict__ out) {
    __shared__ unsigned int slut[16];
    if (threadIdx.x < 16) slut[threadIdx.x] = lut32[threadIdx.x];
    __syncthreads();

    int c = blockIdx.x * 256 + threadIdx.x;
    int w = c & (WW - 1);
    int h = (c >> 9) & (HH - 1);
    int b = c >> 18;
    int hu = (h + HH - 1) & (HH - 1);
    int hd = (h + 1) & (HH - 1);
    int q = w >> 5, o = w & 31;
    int qp = (q + WORDS_PER_ROW - 1) & (WORDS_PER_ROW - 1);
    int qn = (q + 1) & (WORDS_PER_ROW - 1);
    int base = b * (HH * WORDS_PER_ROW);
    const unsigned int* Ru = Fcur + base + hu * WORDS_PER_ROW;
    const unsigned int* Rm = Fcur + base + h * WORDS_PER_ROW;
    const unsigned int* Rd = Fcur + base + hd * WORDS_PER_ROW;

    auto win3 = [&](const unsigned int* R) -> unsigned int {
        unsigned long long v = ((unsigned long long)R[qn] << 32) | (unsigned long long)R[q];
        unsigned long long ext = (v << 1) | (unsigned long long)(R[qp] >> 31);
        return (unsigned int)(ext >> o) & 7u;
    };
    unsigned int iu = win3(Ru);
    unsigned int im = win3(Rm);
    unsigned int id = win3(Rd);
    unsigned int idx = iu | (im << 3) | (id << 6);
    unsigned int bit = (slut[idx >> 5] >> (idx & 31)) & 1u;

    out[c] = (float)bit;
    unsigned long long m = __ballot(bit != 0u);
    if ((threadIdx.x & 63) == 0) Fnext[c >> 6] = m;
}

// ---------------------------------------------------------------------------
// Launch: LUT build -> init -> 15 steps (ping-pong bit fields in d_ws).
// d_ws layout: [0,64)   LUT (8 u64 = 16 u32)
//              [256, 256+N/8)          field A (N/8 bytes = 256 KiB)
//              [256+N/8, 256+2*N/8)    field B
// Total ~524.5 KiB of workspace.
// ---------------------------------------------------------------------------
extern "C" void kernel_launch(void* const* d_in, const int* in_sizes, int n_in,
                              void* d_out, int out_size, void* d_ws, size_t ws_size,
                              hipStream_t stream) {
    const float* f0 = (const float*)d_in[0];
    const float* W1 = (const float*)d_in[1];
    const float* b1 = (const float*)d_in[2];
    const float* W2 = (const float*)d_in[3];
    const float* b2 = (const float*)d_in[4];
    float* out = (float*)d_out;

    const int n = in_sizes[0];        // B*1*H*W = 2,097,152
    const int hid = in_sizes[2];      // 64
    const int T = out_size / n;       // 16

    char* ws = (char*)d_ws;
    unsigned long long* lut64 = (unsigned long long*)ws;
    const unsigned int* lut32 = (const unsigned int*)ws;
    unsigned long long* fA = (unsigned long long*)(ws + 256);
    unsigned long long* fB = (unsigned long long*)(ws + 256 + (size_t)(n / 8));

    build_lut<<<1, 512, 0, stream>>>(W1, b1, W2, b2, hid, lut64);
    init_field<<<n / 256, 256, 0, stream>>>(f0, out, fA);

    for (int t = 1; t < T; ++t) {
        const unsigned int* cur = (const unsigned int*)((t & 1) ? fA : fB);
        unsigned long long* nxt = (t & 1) ? fB : fA;
        step_kernel<<<n / 256, 256, 0, stream>>>(cur, nxt, lut32, out + (size_t)t * n);
    }
}

// Round 2
// 67.195 us; speedup vs baseline: 2.3332x; 2.3332x over previous
//
#include <hip/hip_runtime.h>

// Problem geometry (from reference setup_inputs): B=8, H=512, W=512, HID=64, T=16.
#define HH 512
#define WW 512
#define WORDS_PER_ROW (WW / 32)   // 16
#define RO 16                     // output rows owned per block
#define HALO 15                   // T-1 steps of temporal blocking
#define ROWS (RO + 2 * HALO)      // 46 rows staged in LDS

// ---------------------------------------------------------------------------
// Kernel 1: build the 512-entry rule (exact fp32, ascending-n order — matches
// the reference einsum rounding; verified absmax 0.0 in round 1), then expand
// it into a 4096-entry pair-LUT: idx12 = u4 | m4<<4 | d4<<8 (4-bit column
// windows of rows up/mid/down), entry = 2 bits = rule for cells (c, c+1).
// Packed 16 entries per u32 -> 256 u32 = 1 KiB.
// ---------------------------------------------------------------------------
__global__ void build_lut(const float* __restrict__ W1, const float* __restrict__ b1,
                          const float* __restrict__ W2, const float* __restrict__ b2,
                          int hid, unsigned int* __restrict__ lut12g) {
    __shared__ unsigned int rule[512];
    int p = threadIdx.x;  // 0..511
    float logit = b2[0];
    for (int k = 0; k < hid; ++k) {
        float a = b1[k];
#pragma unroll
        for (int n = 0; n < 9; ++n)
            if (p & (1 << n)) a += W1[n * hid + k];
        logit += fmaxf(a, 0.0f) * W2[k];
    }
    rule[p] = (logit > 0.0f) ? 1u : 0u;
    __syncthreads();

    if (p < 256) {  // each thread packs one u32 word = 16 pair-entries
        unsigned int wv = 0;
#pragma unroll
        for (int k = 0; k < 16; ++k) {
            unsigned int e = (unsigned int)p * 16u + k;      // 12-bit index
            unsigned int u = e & 15u, m = (e >> 4) & 15u, d = (e >> 8) & 15u;
            unsigned int i0 = (u & 7u) | ((m & 7u) << 3) | ((d & 7u) << 6);
            unsigned int i1 = (u >> 1) | ((m >> 1) << 3) | ((d >> 1) << 6);
            unsigned int bits = rule[i0] | (rule[i1] << 1);
            wv |= bits << (2 * k);
        }
        lut12g[p] = wv;
    }
}

// ---------------------------------------------------------------------------
// Kernel 2: out[0] = f0 (verbatim floats); bit-pack (f0 > 0.5) into field.
// ---------------------------------------------------------------------------
__global__ __launch_bounds__(256) void init_field(const float* __restrict__ f0,
                                                  float* __restrict__ out,
                                                  unsigned long long* __restrict__ field) {
    int c = blockIdx.x * 256 + threadIdx.x;
    float v = f0[c];
    out[c] = v;
    unsigned long long m = __ballot(v > 0.5f);
    if ((threadIdx.x & 63) == 0) field[c >> 6] = m;
}

// ---------------------------------------------------------------------------
// Kernel 3: ALL 15 steps fused via temporal blocking.
// Block = 512 threads, owns RO=16 rows of one image. Loads 46 halo rows of the
// step-0 bit field into LDS, ping-pongs two LDS buffers through 15 steps with
// a shrinking valid region [t, 46-t), and after each step emits its owned 16
// rows (8192 cells) as coalesced float4 stores.
// ---------------------------------------------------------------------------
__global__ __launch_bounds__(512) void fused_steps(const unsigned int* __restrict__ field,
                                                   const unsigned int* __restrict__ lut12g,
                                                   float* __restrict__ out,
                                                   int n, int T) {
    __shared__ unsigned int lut[256];
    __shared__ unsigned int bufA[ROWS * WORDS_PER_ROW];
    __shared__ unsigned int bufB[ROWS * WORDS_PER_ROW];

    const int tid = threadIdx.x;
    const int b = blockIdx.x >> 5;           // image
    const int r0 = (blockIdx.x & 31) * RO;   // first owned global row
    const unsigned int* F = field + b * (HH * WORDS_PER_ROW);
    float* outb = out + (size_t)b * (HH * WW);

    if (tid < 256) lut[tid] = lut12g[tid];
    for (int i = tid; i < ROWS * WORDS_PER_ROW; i += 512) {
        int l = i >> 4, w = i & 15;
        int g = (r0 - HALO + l) & (HH - 1);  // wrap in H
        bufA[i] = F[g * WORDS_PER_ROW + w];
    }
    __syncthreads();

    unsigned int* oldb = bufA;
    unsigned int* newb = bufB;

    for (int t = 1; t < T; ++t) {
        const int lo = t, hi = ROWS - t;     // valid new rows [lo, hi)
        for (int l = lo + (tid >> 4); l < hi; l += 32) {
            const int w = tid & 15;
            const int wp = (w + 15) & 15, wn = (w + 1) & 15;
            const unsigned int* Ru = oldb + (l - 1) * WORDS_PER_ROW;
            const unsigned int* Rm = oldb + l * WORDS_PER_ROW;
            const unsigned int* Rd = oldb + (l + 1) * WORDS_PER_ROW;
            // 34-bit extended window: bit k = column (w*32 + k - 1), wrap in W
            unsigned long long eu = ((((unsigned long long)Ru[wn] << 32) | Ru[w]) << 1) | (Ru[wp] >> 31);
            unsigned long long em = ((((unsigned long long)Rm[wn] << 32) | Rm[w]) << 1) | (Rm[wp] >> 31);
            unsigned long long ed = ((((unsigned long long)Rd[wn] << 32) | Rd[w]) << 1) | (Rd[wp] >> 31);
            unsigned int ow = 0;
#pragma unroll
            for (int j = 0; j < 16; ++j) {
                unsigned int idx = (unsigned int)((eu >> (2 * j)) & 15ull)
                                 | ((unsigned int)((em >> (2 * j)) & 15ull) << 4)
                                 | ((unsigned int)((ed >> (2 * j)) & 15ull) << 8);
                unsigned int bits = (lut[idx >> 4] >> ((idx & 15u) * 2)) & 3u;
                ow |= bits << (2 * j);
            }
            newb[l * WORDS_PER_ROW + w] = ow;
        }
        __syncthreads();
        // Emit owned rows (local rows HALO..HALO+15) for step t: 8192 cells,
        // 4 cells/thread/rep as one float4 -> perfectly coalesced.
        float* outt = outb + (size_t)t * n;
#pragma unroll
        for (int rep = 0; rep < 4; ++rep) {
            int cell = (rep * 512 + tid) * 4;          // 0..8188, step 4
            int lr = cell >> 9;                        // owned row 0..15
            int col = cell & 511;
            unsigned int wv = newb[(HALO + lr) * WORDS_PER_ROW + (col >> 5)];
            unsigned int nib = (wv >> (col & 31)) & 15u;
            float4 v;
            v.x = (float)(nib & 1u);
            v.y = (float)((nib >> 1) & 1u);
            v.z = (float)((nib >> 2) & 1u);
            v.w = (float)(nib >> 3);
            *(float4*)(outt + (size_t)(r0 + lr) * WW + col) = v;
        }
        // swap buffers; single sync per iteration is safe: next compute only
        // WRITES the buffer nobody reads anymore and READS the one emission reads.
        unsigned int* tmp = oldb; oldb = newb; newb = tmp;
        if (t + 1 < T) __syncthreads();
    }
}

// ---------------------------------------------------------------------------
// Launch: build_lut -> init_field -> fused_steps (3 dispatches total).
// d_ws layout: [0, 1024)            12-bit pair-LUT (256 u32)
//              [1024, 1024 + n/8)   packed step-0 bit field (256 KiB)
// ---------------------------------------------------------------------------
extern "C" void kernel_launch(void* const* d_in, const int* in_sizes, int n_in,
                              void* d_out, int out_size, void* d_ws, size_t ws_size,
                              hipStream_t stream) {
    const float* f0 = (const float*)d_in[0];
    const float* W1 = (const float*)d_in[1];
    const float* b1 = (const float*)d_in[2];
    const float* W2 = (const float*)d_in[3];
    const float* b2 = (const float*)d_in[4];
    float* out = (float*)d_out;

    const int n = in_sizes[0];        // B*1*H*W = 2,097,152
    const int hid = in_sizes[2];      // 64
    const int T = out_size / n;       // 16
    const int B = n / (HH * WW);      // 8

    char* ws = (char*)d_ws;
    unsigned int* lut12 = (unsigned int*)ws;
    unsigned long long* fld = (unsigned long long*)(ws + 1024);

    build_lut<<<1, 512, 0, stream>>>(W1, b1, W2, b2, hid, lut12);
    init_field<<<n / 256, 256, 0, stream>>>(f0, out, fld);
    fused_steps<<<B * (HH / RO), 512, 0, stream>>>((const unsigned int*)fld, lut12, out, n, T);
}

// Round 3
// 66.686 us; speedup vs baseline: 2.3511x; 1.0076x over previous
//
#include <hip/hip_runtime.h>

// Problem geometry: B=8, H=512, W=512, HID=64, T=16.
#define HH 512
#define WW 512
#define WPR 16                    // u32 words per global row
#define RO 16                     // owned rows per block
#define HALO 15                   // T-1 steps of temporal blocking
#define ROWS (RO + 2 * HALO)      // 46 rows staged in LDS
#define OW 8                      // owned words per block (256 cols)
#define TW 10                     // tile words = owned + 1 halo word each side
// Halo-word correctness: the dependency cone grows 1 bit/step; needed bits of
// the left halo word at step t are >= 17+t while bits corrupted by the missing
// word-(-1) input are <= t-1 (induction), so +/-1 halo word covers all 15 steps.

// ---------------------------------------------------------------------------
// Kernel 1: out[0] = f0 (verbatim floats); bit-pack (f0 > 0.5) into field.
// ---------------------------------------------------------------------------
__global__ __launch_bounds__(256) void init_field(const float* __restrict__ f0,
                                                  float* __restrict__ out,
                                                  unsigned long long* __restrict__ field) {
    int c = blockIdx.x * 256 + threadIdx.x;
    float v = f0[c];
    out[c] = v;
    unsigned long long m = __ballot(v > 0.5f);
    if ((threadIdx.x & 63) == 0) field[c >> 6] = m;
}

// ---------------------------------------------------------------------------
// Kernel 2: everything else. 512 blocks (8 images x 32 row-groups x 2 col-
// groups) x 512 threads = 2 blocks/CU. Each block:
//   a) builds the 512-entry rule in LDS (exact fp32, same add order as the
//      reference einsum -- verified absmax 0.0 in rounds 1-2),
//   b) expands it to the 4096-entry 2-cells-per-lookup pair-LUT (1 KiB),
//   c) loads its 46-row x 10-word bit tile,
//   d) runs 15 steps with ONE barrier per step: compute -> sync -> emit,
//      where emit (reads newb) overlaps the next compute (writes oldb).
// ---------------------------------------------------------------------------
__global__ __launch_bounds__(512) void mega(const unsigned int* __restrict__ field,
                                            const float* __restrict__ W1,
                                            const float* __restrict__ b1,
                                            const float* __restrict__ W2,
                                            const float* __restrict__ b2,
                                            int hid, float* __restrict__ out,
                                            int n, int T) {
    __shared__ unsigned int rule[512];
    __shared__ unsigned int lut[256];
    __shared__ unsigned int bufA[ROWS * TW];
    __shared__ unsigned int bufB[ROWS * TW];

    const int tid = threadIdx.x;
    const int cg = blockIdx.x & 1;
    const int rg = (blockIdx.x >> 1) & 31;
    const int b  = blockIdx.x >> 6;
    const int r0 = rg * RO;          // first owned global row
    const int q0 = cg * OW;          // first owned global word
    const int c0 = cg * (OW * 32);   // first owned global column

    // (a) rule table — source identical to the verified build_lut.
    {
        int p = tid;  // 0..511
        float logit = b2[0];
        for (int k = 0; k < hid; ++k) {
            float a = b1[k];
#pragma unroll
            for (int nn = 0; nn < 9; ++nn)
                if (p & (1 << nn)) a += W1[nn * hid + k];
            logit += fmaxf(a, 0.0f) * W2[k];
        }
        rule[p] = (logit > 0.0f) ? 1u : 0u;
    }
    __syncthreads();

    // (b) pair-LUT: idx12 = u4 | m4<<4 | d4<<8 -> 2 bits (cells c, c+1).
    if (tid < 256) {
        unsigned int wv = 0;
#pragma unroll
        for (int k = 0; k < 16; ++k) {
            unsigned int e = (unsigned int)tid * 16u + k;
            unsigned int u = e & 15u, m = (e >> 4) & 15u, d = (e >> 8) & 15u;
            unsigned int i0 = (u & 7u) | ((m & 7u) << 3) | ((d & 7u) << 6);
            unsigned int i1 = (u >> 1) | ((m >> 1) << 3) | ((d >> 1) << 6);
            wv |= (rule[i0] | (rule[i1] << 1)) << (2 * k);
        }
        lut[tid] = wv;
    }

    // (c) load bit tile (wrap in H via &511, in W via &15).
    {
        const unsigned int* F = field + b * (HH * WPR);
        for (int i = tid; i < ROWS * TW; i += 512) {
            int l = i / TW, tw = i - l * TW;
            int g  = (r0 - HALO + l) & (HH - 1);
            int gw = (q0 - 1 + tw) & (WPR - 1);
            bufA[i] = F[g * WPR + gw];
        }
    }
    __syncthreads();

    unsigned int* oldb = bufA;
    unsigned int* newb = bufB;
    float* outb = out + (size_t)b * (HH * WW);

    for (int t = 1; t < T; ++t) {
        // compute: valid new rows [t, ROWS-t); max 44*10=440 items < 512 thr.
        const int hi = ROWS - t;
        const int lq = tid / TW;
        const int w  = tid - lq * TW;
        const int l  = t + lq;
        if (l < hi) {
            const unsigned int* Ru = oldb + (l - 1) * TW;
            const unsigned int* Rm = oldb + l * TW;
            const unsigned int* Rd = oldb + (l + 1) * TW;
            const int wl = (w == 0) ? 0 : w - 1;       // garbage-safe (cone)
            const int wn = (w == TW - 1) ? TW - 1 : w + 1;
            unsigned long long eu = ((((unsigned long long)Ru[wn] << 32) | Ru[w]) << 1) | (Ru[wl] >> 31);
            unsigned long long em = ((((unsigned long long)Rm[wn] << 32) | Rm[w]) << 1) | (Rm[wl] >> 31);
            unsigned long long ed = ((((unsigned long long)Rd[wn] << 32) | Rd[w]) << 1) | (Rd[wl] >> 31);
            unsigned int ow = 0;
#pragma unroll
            for (int j = 0; j < 16; ++j) {
                unsigned int idx = (unsigned int)((eu >> (2 * j)) & 15ull)
                                 | ((unsigned int)((em >> (2 * j)) & 15ull) << 4)
                                 | ((unsigned int)((ed >> (2 * j)) & 15ull) << 8);
                ow |= ((lut[idx >> 4] >> ((idx & 15u) * 2)) & 3u) << (2 * j);
            }
            newb[l * TW + w] = ow;
        }
        __syncthreads();   // newb complete; all reads of oldb done.

        // emit step t: owned 16 rows x 256 cols = 4096 cells, 2 passes of
        // 512 contiguous float4 stores. Overlaps next step's compute (which
        // writes only oldb) -- no second barrier needed.
        float* outt = outb + (size_t)t * n;
#pragma unroll
        for (int rep = 0; rep < 2; ++rep) {
            int cell = (rep * 512 + tid) * 4;          // 0..4092, step 4
            int lr  = cell >> 8;                       // owned row 0..15
            int col = cell & 255;                      // owned col
            unsigned int wv = newb[(HALO + lr) * TW + 1 + (col >> 5)];
            unsigned int nib = (wv >> (col & 31)) & 15u;
            float4 v;
            v.x = (float)(nib & 1u);
            v.y = (float)((nib >> 1) & 1u);
            v.z = (float)((nib >> 2) & 1u);
            v.w = (float)(nib >> 3);
            *(float4*)(outt + (size_t)(r0 + lr) * WW + c0 + col) = v;
        }
        unsigned int* tmp = oldb; oldb = newb; newb = tmp;
    }
}

// ---------------------------------------------------------------------------
// Launch: init_field -> mega (2 dispatches).
// d_ws: [0, n/8) packed step-0 bit field (256 KiB).
// ---------------------------------------------------------------------------
extern "C" void kernel_launch(void* const* d_in, const int* in_sizes, int n_in,
                              void* d_out, int out_size, void* d_ws, size_t ws_size,
                              hipStream_t stream) {
    const float* f0 = (const float*)d_in[0];
    const float* W1 = (const float*)d_in[1];
    const float* b1 = (const float*)d_in[2];
    const float* W2 = (const float*)d_in[3];
    const float* b2 = (const float*)d_in[4];
    float* out = (float*)d_out;

    const int n = in_sizes[0];        // B*1*H*W = 2,097,152
    const int hid = in_sizes[2];      // 64
    const int T = out_size / n;       // 16
    const int B = n / (HH * WW);      // 8

    unsigned long long* fld = (unsigned long long*)d_ws;

    init_field<<<n / 256, 256, 0, stream>>>(f0, out, fld);
    mega<<<B * (HH / RO) * 2, 512, 0, stream>>>((const unsigned int*)fld,
                                                W1, b1, W2, b2, hid, out, n, T);
}